// Round 3
// baseline (593.577 us; speedup 1.0000x reference)
//
#include <hip/hip_runtime.h>

// Butterfly (untied, increasing stride), batch=32768, n=1024, m=10 stages, nstack=1.
//
// Round-2: round-0 redesign with LDS cut 80 KB -> 48 KB (suspected cause of the
// 4x container failure: 80 KB static __shared__ exceeds the 64 KB default
// per-block LDS limit; launch failure inside graph capture aborts the harness).
//  * Cross stages 2..7 staged once per block into LDS (48 KB), pre-permuted
//    per-(p,lane) with the self/partner swap pre-applied -> conflict-free,
//    statically-addressed ds_read_b64 per stage, no global gather, no cndmask.
//  * Intra stages 0,1,8,9 read float4 twiddles from global (L1/L2-resident,
//    same pattern as the harness-verified 282.9us kernel).
//  * Grid 512 blocks, each processes 4 chunks of 16 rows with register
//    double-buffered input -> HBM latency hidden, staging amortized 16x.
//  * __launch_bounds__(256,1): lifts the arch-VGPR cap to 256 so vA+vB (128
//    regs) + temporaries fit with no scratch spill (old kernel: WRITE_SIZE
//    1.47x output = ~60 MiB suspected spill traffic at the 128-reg cap).
//
// Element->lane layout per wave (4 rows): e = (p>>2)*256 + lane*4 + (p&3),
// v[q][p].x = row 2q, .y = row 2q+1.
//   stages 0,1  : intra-lane pairs via p-bit 0/1   -> float4 twiddle per pair
//   stages 2..7 : cross-lane, __shfl_xor mask s>>2 -> float2 (t_self,t_partner)
//   stages 8,9  : intra-lane pairs via p-bit 2/3   -> float4 twiddle per pair

constexpr int N = 1024;
constexpr int CHUNKS = 4;
constexpr int ROWS_PER_CHUNK = 16;                       // 4 waves x 4 rows
constexpr int ROWS_PER_BLOCK = CHUNKS * ROWS_PER_CHUNK;  // 64

// LDS: cross stages only (2..7), [st-2][p:16][lane:64] float2 = 8 KB/stage, 48 KB.

template<int STAGE>
__device__ __forceinline__ void do_stage(float2 (&v)[2][16],
                                         const float* __restrict__ tl,
                                         const float* __restrict__ tw,
                                         const int lane)
{
    constexpr int s = 1 << STAGE;

    if constexpr (s >= 4 && s <= 128) {
        // cross-lane: partner is lane ^ (s>>2); twiddle pre-swapped per lane, from LDS
        constexpr int m = s >> 2;
        const float* base = tl + (STAGE - 2) * 2048;
        #pragma unroll
        for (int p = 0; p < 16; ++p) {
            const float2 tt = *(const float2*)(base + (((p << 6) | lane) << 1));
            #pragma unroll
            for (int q = 0; q < 2; ++q) {
                const float px = __shfl_xor(v[q][p].x, m, 64);
                const float py = __shfl_xor(v[q][p].y, m, 64);
                v[q][p].x = tt.x * v[q][p].x + tt.y * px;
                v[q][p].y = tt.x * v[q][p].y + tt.y * py;
            }
        }
    } else {
        // intra-lane: pair (p, p|pm); float4 twiddle straight from global (L2-hot)
        constexpr int pm = (s == 1) ? 1 : (s == 2) ? 2 : (s == 256) ? 4 : 8;
        const float* tws = tw + (STAGE << 11);
        #pragma unroll
        for (int p = 0; p < 16; ++p) {
            if (p & pm) continue;
            const int p2 = p | pm;
            const int e  = ((p >> 2) << 8) | (lane << 2) | (p & 3);  // low element
            const int pr = ((e >> (STAGE + 1)) << STAGE) | (e & (s - 1));
            const float4 t4 = *(const float4*)(tws + pr * 4); // t00 t01 t10 t11
            #pragma unroll
            for (int q = 0; q < 2; ++q) {
                const float2 a = v[q][p];
                const float2 b = v[q][p2];
                v[q][p].x  = t4.x * a.x + t4.y * b.x;
                v[q][p].y  = t4.x * a.y + t4.y * b.y;
                v[q][p2].x = t4.z * a.x + t4.w * b.x;
                v[q][p2].y = t4.z * a.y + t4.w * b.y;
            }
        }
    }
}

__device__ __forceinline__ void load_rows(float2 (&v)[2][16],
                                          const float* __restrict__ x,
                                          const size_t row0, const int lane)
{
    #pragma unroll
    for (int q = 0; q < 2; ++q) {
        const float* p0 = x + (row0 + 2 * q) * N + lane * 4;
        const float* p1 = p0 + N;
        #pragma unroll
        for (int r = 0; r < 4; ++r) {
            const float4 a = *(const float4*)(p0 + r * 256);
            const float4 b = *(const float4*)(p1 + r * 256);
            v[q][r * 4 + 0] = make_float2(a.x, b.x);
            v[q][r * 4 + 1] = make_float2(a.y, b.y);
            v[q][r * 4 + 2] = make_float2(a.z, b.z);
            v[q][r * 4 + 3] = make_float2(a.w, b.w);
        }
    }
}

__device__ __forceinline__ void compute_store(float2 (&v)[2][16],
                                              const float* __restrict__ tl,
                                              const float* __restrict__ tw,
                                              float* __restrict__ out,
                                              const size_t row0, const int lane,
                                              const float4 (&bb)[4])
{
    do_stage<0>(v, tl, tw, lane);
    do_stage<1>(v, tl, tw, lane);
    do_stage<2>(v, tl, tw, lane);
    do_stage<3>(v, tl, tw, lane);
    do_stage<4>(v, tl, tw, lane);
    do_stage<5>(v, tl, tw, lane);
    do_stage<6>(v, tl, tw, lane);
    do_stage<7>(v, tl, tw, lane);
    do_stage<8>(v, tl, tw, lane);
    do_stage<9>(v, tl, tw, lane);

    #pragma unroll
    for (int q = 0; q < 2; ++q) {
        float* o0 = out + (row0 + 2 * q) * N + lane * 4;
        float* o1 = o0 + N;
        #pragma unroll
        for (int r = 0; r < 4; ++r) {
            float4 a, b;
            a.x = v[q][r * 4 + 0].x + bb[r].x;  b.x = v[q][r * 4 + 0].y + bb[r].x;
            a.y = v[q][r * 4 + 1].x + bb[r].y;  b.y = v[q][r * 4 + 1].y + bb[r].y;
            a.z = v[q][r * 4 + 2].x + bb[r].z;  b.z = v[q][r * 4 + 2].y + bb[r].z;
            a.w = v[q][r * 4 + 3].x + bb[r].w;  b.w = v[q][r * 4 + 3].y + bb[r].w;
            *(float4*)(o0 + r * 256) = a;
            *(float4*)(o1 + r * 256) = b;
        }
    }
}

__global__ __launch_bounds__(256, 1)
void butterfly_kernel(const float* __restrict__ x,
                      const float* __restrict__ tw,    // [10][512][2][2]
                      const float* __restrict__ bias,  // [1024]
                      float* __restrict__ out)
{
    __shared__ __align__(16) float tl[6 * 2048];       // 48 KB, stages 2..7

    const int t    = threadIdx.x;
    const int lane = t & 63;
    const int g    = t >> 6;

    // ---- stage cross twiddles (2..7) into LDS, pre-swapped per lane.
    // Each thread writes 4 (p,lane) float2 entries per stage.
    #pragma unroll
    for (int st = 2; st <= 7; ++st) {
        const int s = 1 << st;
        #pragma unroll
        for (int k = 0; k < 4; ++k) {
            const int p  = (g << 2) | k;
            const int e  = ((p >> 2) << 8) | (lane << 2) | (p & 3);
            const int i  = (e >> st) & 1;
            const int pr = ((e >> (st + 1)) << st) | (e & (s - 1));
            const float2 tt = *(const float2*)(tw + (st << 11) + pr * 4 + i * 2);
            const float2 w  = i ? make_float2(tt.y, tt.x) : tt;   // (t_self, t_partner)
            *(float2*)(tl + (st - 2) * 2048 + (((p << 6) | lane) << 1)) = w;
        }
    }

    // bias held in registers for the whole block's lifetime
    float4 bb[4];
    #pragma unroll
    for (int r = 0; r < 4; ++r)
        bb[r] = *(const float4*)(bias + r * 256 + lane * 4);

    __syncthreads();   // only barrier in the kernel

    const size_t base = (size_t)blockIdx.x * ROWS_PER_BLOCK + (size_t)(g * 4);

    // ---- 4 chunks, register double-buffered: prefetch next while computing current
    float2 vA[2][16], vB[2][16];
    load_rows(vA, x, base + 0 * ROWS_PER_CHUNK, lane);
    load_rows(vB, x, base + 1 * ROWS_PER_CHUNK, lane);
    compute_store(vA, tl, tw, out, base + 0 * ROWS_PER_CHUNK, lane, bb);
    load_rows(vA, x, base + 2 * ROWS_PER_CHUNK, lane);
    compute_store(vB, tl, tw, out, base + 1 * ROWS_PER_CHUNK, lane, bb);
    load_rows(vB, x, base + 3 * ROWS_PER_CHUNK, lane);
    compute_store(vA, tl, tw, out, base + 2 * ROWS_PER_CHUNK, lane, bb);
    compute_store(vB, tl, tw, out, base + 3 * ROWS_PER_CHUNK, lane, bb);
}

extern "C" void kernel_launch(void* const* d_in, const int* in_sizes, int n_in,
                              void* d_out, int out_size, void* d_ws, size_t ws_size,
                              hipStream_t stream) {
    const float* x    = (const float*)d_in[0];   // [batch][1024]
    const float* tw   = (const float*)d_in[1];   // [1][10][512][2][2]
    const float* bias = (const float*)d_in[2];   // [1024]
    float* out        = (float*)d_out;

    const int batch  = in_sizes[0] / N;          // 32768
    const int blocks = batch / ROWS_PER_BLOCK;   // 512
    hipLaunchKernelGGL(butterfly_kernel, dim3(blocks), dim3(256), 0, stream,
                       x, tw, bias, out);
}

// Round 4
// 553.047 us; speedup vs baseline: 1.0733x; 1.0733x over previous
//
#include <hip/hip_runtime.h>

// Butterfly (untied, increasing stride), batch=32768, n=1024, m=10 stages, nstack=1.
//
// Round-4: round-3 post-mortem showed the regression was pure VGPR spill
// (VGPR=256, WRITE_SIZE 3.9x output, FETCH 3.8x input, occupancy 11%) caused by
// the register double-buffer (vA+vB live across compute). This round keeps the
// verified LDS twiddle staging and removes the spill source:
//  * single v[2][16] per wave, load->compute->store per chunk, chunk loop
//    forced #pragma unroll 1 so the compiler cannot re-interleave chunks.
//  * __launch_bounds__(256,2) -> 128-VGPR cap (the proven baseline regime).
//  * grid 1024 x 2 chunks: staging amortized 2x; 48 KB LDS allows 3 blocks/CU.
//  * cross-stage LDS table packed [p/2][lane] float4 -> 8 ds_read_b128/stage,
//    lane-consecutive 16 B (optimal LDS pattern), pre-swapped per lane so the
//    baseline's per-lane cndmask selects are gone.
//  * intra stages 0,1,8,9 read float4 twiddles from global (proven baseline path).
//
// Element->lane layout per wave (4 rows): e = (p>>2)*256 + lane*4 + (p&3),
// v[q][p].x = row 2q, .y = row 2q+1.
//   stages 0,1  : intra-lane pairs via p-bit 0/1   -> float4 twiddle per pair
//   stages 2..7 : cross-lane, __shfl_xor mask s>>2 -> (t_self,t_partner) from LDS
//   stages 8,9  : intra-lane pairs via p-bit 2/3   -> float4 twiddle per pair

constexpr int N = 1024;
constexpr int CHUNKS = 2;
constexpr int ROWS_PER_CHUNK = 16;                       // 4 waves x 4 rows
constexpr int ROWS_PER_BLOCK = CHUNKS * ROWS_PER_CHUNK;  // 32

// LDS: cross stages 2..7, [st-2][ppair:8][lane:64] float4 = 8 KB/stage, 48 KB.
// Entry (ppair,lane): .xy = (t_self,t_partner) for p=2*ppair, .zw = for p=2*ppair+1.

template<int STAGE>
__device__ __forceinline__ void do_stage(float2 (&v)[2][16],
                                         const float* __restrict__ tl,
                                         const float* __restrict__ tw,
                                         const int lane)
{
    constexpr int s = 1 << STAGE;

    if constexpr (s >= 4 && s <= 128) {
        // cross-lane: partner is lane ^ (s>>2); twiddles pre-swapped per lane, from LDS
        constexpr int m = s >> 2;
        const float* base = tl + (STAGE - 2) * 2048;
        #pragma unroll
        for (int pp = 0; pp < 8; ++pp) {
            const float4 t4 = *(const float4*)(base + (((pp << 6) | lane) << 2));
            const int p0 = 2 * pp, p1 = 2 * pp + 1;
            #pragma unroll
            for (int q = 0; q < 2; ++q) {
                float px = __shfl_xor(v[q][p0].x, m, 64);
                float py = __shfl_xor(v[q][p0].y, m, 64);
                v[q][p0].x = t4.x * v[q][p0].x + t4.y * px;
                v[q][p0].y = t4.x * v[q][p0].y + t4.y * py;
                px = __shfl_xor(v[q][p1].x, m, 64);
                py = __shfl_xor(v[q][p1].y, m, 64);
                v[q][p1].x = t4.z * v[q][p1].x + t4.w * px;
                v[q][p1].y = t4.z * v[q][p1].y + t4.w * py;
            }
        }
    } else {
        // intra-lane: pair (p, p|pm); float4 twiddle straight from global (L2-hot)
        constexpr int pm = (s == 1) ? 1 : (s == 2) ? 2 : (s == 256) ? 4 : 8;
        const float* tws = tw + (STAGE << 11);
        #pragma unroll
        for (int p = 0; p < 16; ++p) {
            if (p & pm) continue;
            const int p2 = p | pm;
            const int e  = ((p >> 2) << 8) | (lane << 2) | (p & 3);  // low element
            const int pr = ((e >> (STAGE + 1)) << STAGE) | (e & (s - 1));
            const float4 t4 = *(const float4*)(tws + pr * 4); // t00 t01 t10 t11
            #pragma unroll
            for (int q = 0; q < 2; ++q) {
                const float2 a = v[q][p];
                const float2 b = v[q][p2];
                v[q][p].x  = t4.x * a.x + t4.y * b.x;
                v[q][p].y  = t4.x * a.y + t4.y * b.y;
                v[q][p2].x = t4.z * a.x + t4.w * b.x;
                v[q][p2].y = t4.z * a.y + t4.w * b.y;
            }
        }
    }
}

__global__ __launch_bounds__(256, 2)
void butterfly_kernel(const float* __restrict__ x,
                      const float* __restrict__ tw,    // [10][512][2][2]
                      const float* __restrict__ bias,  // [1024]
                      float* __restrict__ out)
{
    __shared__ __align__(16) float tl[6 * 2048];       // 48 KB, stages 2..7

    const int t    = threadIdx.x;
    const int lane = t & 63;
    const int g    = t >> 6;

    // ---- stage cross twiddles (2..7) into LDS, pre-swapped per lane.
    // Each thread writes 4 (p,lane) float2 entries per stage into its float4 slot.
    #pragma unroll
    for (int st = 2; st <= 7; ++st) {
        const int s = 1 << st;
        #pragma unroll
        for (int k = 0; k < 4; ++k) {
            const int p  = (g << 2) | k;
            const int e  = ((p >> 2) << 8) | (lane << 2) | (p & 3);
            const int i  = (e >> st) & 1;
            const int pr = ((e >> (st + 1)) << st) | (e & (s - 1));
            const float2 tt = *(const float2*)(tw + (st << 11) + pr * 4 + i * 2);
            const float2 w  = i ? make_float2(tt.y, tt.x) : tt;   // (t_self, t_partner)
            *(float2*)(tl + (st - 2) * 2048 +
                       ((((p >> 1) << 6) | lane) << 2) + ((p & 1) << 1)) = w;
        }
    }

    __syncthreads();   // only barrier in the kernel

    const size_t base = (size_t)blockIdx.x * ROWS_PER_BLOCK + (size_t)(g * 4);

    // ---- chunks: load -> 10 stages -> store. No cross-chunk register state.
    #pragma unroll 1
    for (int c = 0; c < CHUNKS; ++c) {
        const size_t row0 = base + (size_t)c * ROWS_PER_CHUNK;
        float2 v[2][16];   // [row-pair q][position p], .x = row 2q, .y = row 2q+1

        // load: coalesced float4 per row
        #pragma unroll
        for (int q = 0; q < 2; ++q) {
            const float* p0 = x + (row0 + 2 * q) * N + lane * 4;
            const float* p1 = p0 + N;
            #pragma unroll
            for (int r = 0; r < 4; ++r) {
                const float4 a = *(const float4*)(p0 + r * 256);
                const float4 b = *(const float4*)(p1 + r * 256);
                v[q][r * 4 + 0] = make_float2(a.x, b.x);
                v[q][r * 4 + 1] = make_float2(a.y, b.y);
                v[q][r * 4 + 2] = make_float2(a.z, b.z);
                v[q][r * 4 + 3] = make_float2(a.w, b.w);
            }
        }

        do_stage<0>(v, tl, tw, lane);
        do_stage<1>(v, tl, tw, lane);
        do_stage<2>(v, tl, tw, lane);
        do_stage<3>(v, tl, tw, lane);
        do_stage<4>(v, tl, tw, lane);
        do_stage<5>(v, tl, tw, lane);
        do_stage<6>(v, tl, tw, lane);
        do_stage<7>(v, tl, tw, lane);
        do_stage<8>(v, tl, tw, lane);
        do_stage<9>(v, tl, tw, lane);

        // store with bias (bias loaded here, baseline-proven; keeps it out of
        // long-lived registers)
        #pragma unroll
        for (int q = 0; q < 2; ++q) {
            float* o0 = out + (row0 + 2 * q) * N + lane * 4;
            float* o1 = o0 + N;
            #pragma unroll
            for (int r = 0; r < 4; ++r) {
                const float4 bb = *(const float4*)(bias + r * 256 + lane * 4);
                float4 a, b;
                a.x = v[q][r * 4 + 0].x + bb.x;  b.x = v[q][r * 4 + 0].y + bb.x;
                a.y = v[q][r * 4 + 1].x + bb.y;  b.y = v[q][r * 4 + 1].y + bb.y;
                a.z = v[q][r * 4 + 2].x + bb.z;  b.z = v[q][r * 4 + 2].y + bb.z;
                a.w = v[q][r * 4 + 3].x + bb.w;  b.w = v[q][r * 4 + 3].y + bb.w;
                *(float4*)(o0 + r * 256) = a;
                *(float4*)(o1 + r * 256) = b;
            }
        }
    }
}

extern "C" void kernel_launch(void* const* d_in, const int* in_sizes, int n_in,
                              void* d_out, int out_size, void* d_ws, size_t ws_size,
                              hipStream_t stream) {
    const float* x    = (const float*)d_in[0];   // [batch][1024]
    const float* tw   = (const float*)d_in[1];   // [1][10][512][2][2]
    const float* bias = (const float*)d_in[2];   // [1024]
    float* out        = (float*)d_out;

    const int batch  = in_sizes[0] / N;          // 32768
    const int blocks = batch / ROWS_PER_BLOCK;   // 1024
    hipLaunchKernelGGL(butterfly_kernel, dim3(blocks), dim3(256), 0, stream,
                       x, tw, bias, out);
}

// Round 5
// 246.664 us; speedup vs baseline: 2.4064x; 2.2421x over previous
//
#include <hip/hip_runtime.h>

// Butterfly (untied, increasing stride), batch=32768, n=1024, m=10 stages, nstack=1.
//
// Round-5: minimal A/B against the harness-proven 129us baseline.
// Round-4 post-mortem: the chunk loop let LICM hoist the loop-invariant intra-
// stage twiddle loads (32 float4 = 128 VGPRs) above the loop -> spill -> 787 MiB
// FETCH / 524 MiB WRITE, VALUBusy 4.4%. Fix: restore the EXACT baseline
// structure (one 16-row chunk per block, grid 2048, no loops, (256,2) bounds)
// and change ONE thing: cross stages 2..7 read pre-swapped twiddles from a
// 48 KB LDS table (8x ds_read_b128 per stage, conflict-free, no cndmask)
// instead of per-stage global gathers. Intra stages 0,1,8,9 keep the baseline
// global float4 path in straight-line code (nothing hoistable).
//
// Element->lane layout per wave (4 rows): e = (p>>2)*256 + lane*4 + (p&3),
// v[q][p].x = row 2q, .y = row 2q+1.
//   stages 0,1  : intra-lane pairs via p-bit 0/1   -> float4 twiddle per pair
//   stages 2..7 : cross-lane, __shfl_xor mask s>>2 -> (t_self,t_partner) from LDS
//   stages 8,9  : intra-lane pairs via p-bit 2/3   -> float4 twiddle per pair

constexpr int N = 1024;
constexpr int B_ROWS = 4;   // rows per wave
constexpr int WAVES = 4;    // waves per block (block = 256 threads)

// LDS: cross stages 2..7, [st-2][ppair:8][lane:64] float4 = 8 KB/stage, 48 KB.
// Entry (ppair,lane): .xy = (t_self,t_partner) for p=2*ppair, .zw = p=2*ppair+1.

template<int STAGE>
__device__ __forceinline__ void do_stage(float2 (&v)[2][16],
                                         const float* __restrict__ tl,
                                         const float* __restrict__ tw,
                                         const int lane)
{
    constexpr int s = 1 << STAGE;

    if constexpr (s >= 4 && s <= 128) {
        // cross-lane: partner is lane ^ (s>>2); twiddles pre-swapped per lane, LDS
        constexpr int m = s >> 2;
        const float* base = tl + (STAGE - 2) * 2048;
        #pragma unroll
        for (int pp = 0; pp < 8; ++pp) {
            const float4 t4 = *(const float4*)(base + (((pp << 6) | lane) << 2));
            const int p0 = 2 * pp, p1 = 2 * pp + 1;
            #pragma unroll
            for (int q = 0; q < 2; ++q) {
                float px = __shfl_xor(v[q][p0].x, m, 64);
                float py = __shfl_xor(v[q][p0].y, m, 64);
                v[q][p0].x = t4.x * v[q][p0].x + t4.y * px;
                v[q][p0].y = t4.x * v[q][p0].y + t4.y * py;
                px = __shfl_xor(v[q][p1].x, m, 64);
                py = __shfl_xor(v[q][p1].y, m, 64);
                v[q][p1].x = t4.z * v[q][p1].x + t4.w * px;
                v[q][p1].y = t4.z * v[q][p1].y + t4.w * py;
            }
        }
    } else {
        // intra-lane: pair (p, p|pm); float4 twiddle from global (baseline path)
        constexpr int pm = (s == 1) ? 1 : (s == 2) ? 2 : (s == 256) ? 4 : 8;
        const float* tws = tw + (STAGE << 11);
        #pragma unroll
        for (int p = 0; p < 16; ++p) {
            if (p & pm) continue;
            const int p2 = p | pm;
            const int e  = ((p >> 2) << 8) | (lane << 2) | (p & 3);  // low element
            const int pr = ((e >> (STAGE + 1)) << STAGE) | (e & (s - 1));
            const float4 t4 = *(const float4*)(tws + pr * 4); // t00 t01 t10 t11
            #pragma unroll
            for (int q = 0; q < 2; ++q) {
                const float2 a = v[q][p];
                const float2 b = v[q][p2];
                v[q][p].x  = t4.x * a.x + t4.y * b.x;
                v[q][p].y  = t4.x * a.y + t4.y * b.y;
                v[q][p2].x = t4.z * a.x + t4.w * b.x;
                v[q][p2].y = t4.z * a.y + t4.w * b.y;
            }
        }
    }
}

__global__ __launch_bounds__(256, 2)
void butterfly_kernel(const float* __restrict__ x,
                      const float* __restrict__ tw,    // [10][512][2][2]
                      const float* __restrict__ bias,  // [1024]
                      float* __restrict__ out)
{
    __shared__ __align__(16) float tl[6 * 2048];       // 48 KB, stages 2..7

    const int t    = threadIdx.x;
    const int lane = t & 63;
    const int g    = t >> 6;

    // ---- stage cross twiddles (2..7) into LDS, pre-swapped per lane.
    // Each thread writes 4 (p,lane) float2 entries per stage into its float4 slot.
    #pragma unroll
    for (int st = 2; st <= 7; ++st) {
        const int s = 1 << st;
        #pragma unroll
        for (int k = 0; k < 4; ++k) {
            const int p  = (g << 2) | k;
            const int e  = ((p >> 2) << 8) | (lane << 2) | (p & 3);
            const int i  = (e >> st) & 1;
            const int pr = ((e >> (st + 1)) << st) | (e & (s - 1));
            const float2 tt = *(const float2*)(tw + (st << 11) + pr * 4 + i * 2);
            const float2 w  = i ? make_float2(tt.y, tt.x) : tt;   // (t_self, t_partner)
            *(float2*)(tl + (st - 2) * 2048 +
                       ((((p >> 1) << 6) | lane) << 2) + ((p & 1) << 1)) = w;
        }
    }

    __syncthreads();   // only barrier in the kernel

    const int waveg = blockIdx.x * WAVES + g;
    const size_t row0 = (size_t)waveg * B_ROWS;

    float2 v[2][16];   // [row-pair q][position p], .x = row 2q, .y = row 2q+1

    // ---- load: coalesced float4 per row (baseline) ----
    #pragma unroll
    for (int q = 0; q < 2; ++q) {
        const float* p0 = x + (row0 + 2 * q) * N + lane * 4;
        const float* p1 = p0 + N;
        #pragma unroll
        for (int r = 0; r < 4; ++r) {
            const float4 a = *(const float4*)(p0 + r * 256);
            const float4 b = *(const float4*)(p1 + r * 256);
            v[q][r * 4 + 0] = make_float2(a.x, b.x);
            v[q][r * 4 + 1] = make_float2(a.y, b.y);
            v[q][r * 4 + 2] = make_float2(a.z, b.z);
            v[q][r * 4 + 3] = make_float2(a.w, b.w);
        }
    }

    // ---- 10 butterfly stages, fully static ----
    do_stage<0>(v, tl, tw, lane);
    do_stage<1>(v, tl, tw, lane);
    do_stage<2>(v, tl, tw, lane);
    do_stage<3>(v, tl, tw, lane);
    do_stage<4>(v, tl, tw, lane);
    do_stage<5>(v, tl, tw, lane);
    do_stage<6>(v, tl, tw, lane);
    do_stage<7>(v, tl, tw, lane);
    do_stage<8>(v, tl, tw, lane);
    do_stage<9>(v, tl, tw, lane);

    // ---- store with bias (baseline) ----
    #pragma unroll
    for (int q = 0; q < 2; ++q) {
        float* o0 = out + (row0 + 2 * q) * N + lane * 4;
        float* o1 = o0 + N;
        #pragma unroll
        for (int r = 0; r < 4; ++r) {
            const float4 bb = *(const float4*)(bias + r * 256 + lane * 4);
            float4 a, b;
            a.x = v[q][r * 4 + 0].x + bb.x;  b.x = v[q][r * 4 + 0].y + bb.x;
            a.y = v[q][r * 4 + 1].x + bb.y;  b.y = v[q][r * 4 + 1].y + bb.y;
            a.z = v[q][r * 4 + 2].x + bb.z;  b.z = v[q][r * 4 + 2].y + bb.z;
            a.w = v[q][r * 4 + 3].x + bb.w;  b.w = v[q][r * 4 + 3].y + bb.w;
            *(float4*)(o0 + r * 256) = a;
            *(float4*)(o1 + r * 256) = b;
        }
    }
}

extern "C" void kernel_launch(void* const* d_in, const int* in_sizes, int n_in,
                              void* d_out, int out_size, void* d_ws, size_t ws_size,
                              hipStream_t stream) {
    const float* x    = (const float*)d_in[0];   // [batch][1024]
    const float* tw   = (const float*)d_in[1];   // [1][10][512][2][2]
    const float* bias = (const float*)d_in[2];   // [1024]
    float* out        = (float*)d_out;

    const int batch  = in_sizes[0] / N;          // 32768
    const int blocks = batch / (B_ROWS * WAVES); // 2048
    hipLaunchKernelGGL(butterfly_kernel, dim3(blocks), dim3(256), 0, stream,
                       x, tw, bias, out);
}